// Round 1
// baseline (174.285 us; speedup 1.0000x reference)
//
#include <hip/hip_runtime.h>
#include <hip/hip_bf16.h>

// Problem constants
#define BATCH 64
#define NATOM 120
#define NNB 10
#define NBOND 250
#define AF 82
#define BF 6
#define HREAL 300
#define HP 320            // padded H (bf16 activation row stride); pad cols hold exact 0
#define NCT32 10          // 10 col-tiles of 32 -> 320
#define MA (BATCH*NATOM)  // 7680  (= 120 * 64)
#define MB (BATCH*NBOND)  // 16000 (= 250 * 64)

typedef short short8 __attribute__((ext_vector_type(8)));   // 8 bf16 (4 VGPRs)
typedef float f32x16 __attribute__((ext_vector_type(16)));  // 32x32 MFMA accumulator
typedef unsigned int u32;
typedef unsigned short u16;

__device__ __forceinline__ float bflo(u32 v) { return __builtin_bit_cast(float, v << 16); }
__device__ __forceinline__ float bfhi(u32 v) { return __builtin_bit_cast(float, v & 0xffff0000u); }
__device__ __forceinline__ u16 f2bf(float f) {
    __hip_bfloat16 h = __float2bfloat16(f);
    return __builtin_bit_cast(u16, h);
}

// ================= prep: both fp32->bf16 convs + all 8 weight packs in ONE launch =================
// block-range dispatch on a 1D grid.
struct PackJob { const float* W; short8* dst; int Kreal, KT, blk0; };
struct Prep {
    const float* a1src; __hip_bfloat16* a1dst;   // [MA][82] -> [MA][96]
    const float* bsrc;  __hip_bfloat16* bdst;    // [MB][6]  -> [MB][32]
    PackJob j[8];
};

#define CONV1_BLKS 2880   // MA*96/256
#define CONV2_BLKS 2000   // MB*32/256
#define PACK_BASE  (CONV1_BLKS + CONV2_BLKS)
#define PACK_BLKS  275
#define PREP_BLKS  (PACK_BASE + PACK_BLKS)   // 5155

__global__ __launch_bounds__(256) void prep_all(Prep cfg) {
    const int bid = blockIdx.x;
    const int tid = threadIdx.x;
    if (bid < CONV1_BLKS) {
        int id = bid * 256 + tid;                 // exact multiple, no guard
        int r = id / 96, c = id - r * 96;
        float f = (c < AF) ? cfg.a1src[(size_t)r * AF + c] : 0.f;
        cfg.a1dst[id] = __float2bfloat16(f);
    } else if (bid < PACK_BASE) {
        int id = (bid - CONV1_BLKS) * 256 + tid;  // exact multiple
        int r = id >> 5, c = id & 31;
        float f = (c < BF) ? cfg.bsrc[(size_t)r * BF + c] : 0.f;
        cfg.bdst[id] = __float2bfloat16(f);
    } else {
        const int pid = bid - PACK_BASE;
        int ji = 0;
#pragma unroll
        for (int i = 1; i < 8; ++i) if (pid >= cfg.j[i].blk0) ji = i;
        const PackJob J = cfg.j[ji];
        int id = (pid - J.blk0) * 256 + tid;
        int n = NCT32 * J.KT * 64;
        if (id >= n) return;
        int lane = id & 63;
        int kt = (id >> 6) % J.KT;
        int ct = id / (J.KT * 64);
        int col = ct * 32 + (lane & 31);
        int kbase = kt * 16 + (lane >> 5) * 8;
        short8 v;
#pragma unroll
        for (int jj = 0; jj < 8; ++jj) {
            int k = kbase + jj;
            float f = (k < J.Kreal && col < HREAL) ? J.W[(size_t)k * HREAL + col] : 0.f;
            v[jj] = (short)f2bf(f);
        }
        J.dst[(size_t)(ct * J.KT + kt) * 64 + lane] = v;
    }
}

// ================= MFMA GEMM device core (32x32x16), 2 waves = 64 rows x 64 cols =================
// out = act(A @ Wp [+ bias] [+ addp]); ct<NCT32 -> out0 (bf16), ct>=NCT32 -> out1 bf16 or out1f fp32.
template<int KT, bool RELU, bool OUT1F, bool ADDF>
__device__ __forceinline__ void gemm_dev(
    int bx, int by, int tid,
    const __hip_bfloat16* __restrict__ A,
    const short8* __restrict__ Wp,
    const float* __restrict__ bias0,
    const float* __restrict__ bias1,
    __hip_bfloat16* __restrict__ out0,
    __hip_bfloat16* __restrict__ out1,
    float* __restrict__ out1f,
    const float* __restrict__ addp) {
    const int lane = tid & 63;
    const int wv   = tid >> 6;            // 0..1
    const int m0   = bx * 64 + wv * 32;
    const int ct0  = by * 2;
    const int r1   = m0 + (lane & 31);
    const int koff = (lane >> 5) * 8;
    constexpr int S = KT * 16;            // row stride of A in elements

    f32x16 acc[2];
#pragma unroll
    for (int r = 0; r < 16; ++r) { acc[0][r] = 0.f; acc[1][r] = 0.f; }

    const short8* w0 = Wp + ((size_t)ct0 * KT) * 64 + lane;
    const short8* w1 = w0 + (size_t)KT * 64;

    short8 a[KT];
#pragma unroll
    for (int kt = 0; kt < KT; ++kt)
        a[kt] = *reinterpret_cast<const short8*>(A + (size_t)r1 * S + kt * 16 + koff);
#pragma unroll
    for (int kt = 0; kt < KT; ++kt) {
        acc[0] = __builtin_amdgcn_mfma_f32_32x32x16_bf16(a[kt], w0[(size_t)kt * 64], acc[0], 0, 0, 0);
        acc[1] = __builtin_amdgcn_mfma_f32_32x32x16_bf16(a[kt], w1[(size_t)kt * 64], acc[1], 0, 0, 0);
    }

#pragma unroll
    for (int c = 0; c < 2; ++c) {
        const int ct = ct0 + c;
        const bool second = (ct >= NCT32);
        const int colb = second ? ct * 32 - HP : ct * 32;
        const int col = colb + (lane & 31);
        const float* bp = second ? bias1 : bias0;
        const float bb = (bp && col < HREAL) ? bp[col] : 0.f;
#pragma unroll
        for (int r = 0; r < 16; ++r) {
            const int row = m0 + (r & 3) + 8 * (r >> 2) + 4 * (lane >> 5);
            float v = acc[c][r] + bb;
            if (ADDF) v += addp[(size_t)row * HP + col];
            if (RELU) v = fmaxf(v, 0.f);
            if (second) {
                if (OUT1F) out1f[(size_t)row * HP + col] = v;
                else       out1[(size_t)row * HP + col] = __float2bfloat16(v);
            } else {
                out0[(size_t)row * HP + col] = __float2bfloat16(v);
            }
        }
    }
}

// ---- input GEMMs: fc1 (600 blocks) + bond dual (2500 blocks) fused in one launch ----
#define FC1_BLKS  (MA/64 * 5)          // 600
#define BOND_BLKS (MB/64 * 10)         // 2500
__global__ __launch_bounds__(128)
void k_input_gemms(const __hip_bfloat16* __restrict__ A1b,
                   const __hip_bfloat16* __restrict__ bondb,
                   const short8* __restrict__ pW1,
                   const short8* __restrict__ pWbd,
                   const float* __restrict__ bgn,
                   __hip_bfloat16* __restrict__ af0,
                   __hip_bfloat16* __restrict__ bondgc,
                   __hip_bfloat16* __restrict__ bnb) {
    const int bid = blockIdx.x;
    if (bid < FC1_BLKS) {
        gemm_dev<6, true, false, false>(bid % (MA/64), bid / (MA/64), threadIdx.x,
                                        A1b, pW1, nullptr, nullptr, af0, nullptr, nullptr, nullptr);
    } else {
        const int b2 = bid - FC1_BLKS;
        gemm_dev<2, false, false, false>(b2 % (MB/64), b2 / (MB/64), threadIdx.x,
                                         bondb, pWbd, bgn, nullptr, bondgc, bnb, nullptr, nullptr);
    }
}

// ---- per-iteration stage 1: Tb = af@W_nei  AND  U = af@W_gaTop + b_gc_atom (fp32) ----
__global__ __launch_bounds__(128)
void k_gemm_nu(const __hip_bfloat16* __restrict__ af, const short8* __restrict__ W,
               const float* __restrict__ bias1,
               __hip_bfloat16* __restrict__ Tb, float* __restrict__ U) {
    gemm_dev<20, false, true, false>(blockIdx.x, blockIdx.y, threadIdx.x,
                                     af, W, nullptr, bias1, Tb, nullptr, U, nullptr);
}

// ---- per-iteration stage 3: afn = relu(U + neib@W_gaBot) ----
__global__ __launch_bounds__(128)
void k_gemm_bot(const __hip_bfloat16* __restrict__ neib, const short8* __restrict__ W,
                const float* __restrict__ U, __hip_bfloat16* __restrict__ afn) {
    gemm_dev<20, true, false, true>(blockIdx.x, blockIdx.y, threadIdx.x,
                                    neib, W, nullptr, nullptr, afn, nullptr, nullptr, U);
}

// ---- final dual GEMM: selfF = af@W_fc2 (ct<10), A2f = af@W_fc2a (ct>=10) ----
__global__ __launch_bounds__(128)
void k_gemm_final(const __hip_bfloat16* __restrict__ af, const short8* __restrict__ W,
                  __hip_bfloat16* __restrict__ selfF, __hip_bfloat16* __restrict__ A2f) {
    gemm_dev<20, false, false, false>(blockIdx.x, blockIdx.y, threadIdx.x,
                                      af, W, nullptr, nullptr, selfF, A2f, nullptr, nullptr);
}

// ================= gather + relu + masked sum (2 rows per block) =================
__global__ __launch_bounds__(320)
void gather_relu_sum_bf(const u32* __restrict__ T,       // [MA][HP/2]
                        const u32* __restrict__ BG,      // [MB][HP/2]
                        const int* __restrict__ ag,
                        const int* __restrict__ bg,
                        const int* __restrict__ maskn,
                        u32* __restrict__ nei) {
    const int bn = blockIdx.x * 2 + threadIdx.x / 160;
    const int t  = threadIdx.x % 160;
    const int b  = bn / NATOM;
    const int base = bn * NNB;
    float lo = 0.f, hi = 0.f;
#pragma unroll
    for (int j = 0; j < NNB; ++j) {
        if (maskn[base + j]) {
            const int a  = ag[base + j];
            const int bo = bg[base + j];
            u32 ta = T[(size_t)(b * NATOM + a) * (HP / 2) + t];
            u32 tb = BG[(size_t)(b * NBOND + bo) * (HP / 2) + t];
            lo += fmaxf(bflo(ta) + bflo(tb), 0.f);
            hi += fmaxf(bfhi(ta) + bfhi(tb), 0.f);
        }
    }
    nei[(size_t)bn * (HP / 2) + t] = (u32)f2bf(lo) | ((u32)f2bf(hi) << 16);
}

// ================= final: out = mask_atoms ? selfF * sum_j(mask ? A2[ag]*bnb[bg] : 0) : 0 =================
__global__ __launch_bounds__(320)
void final_bf(const u32* __restrict__ A2f,
              const u32* __restrict__ bnb,
              const u32* __restrict__ selfF,
              const int* __restrict__ ag,
              const int* __restrict__ bg,
              const int* __restrict__ maskn,
              const int* __restrict__ maska,
              float* __restrict__ out) {      // [MA][300] fp32
    const int bn = blockIdx.x * 2 + threadIdx.x / 160;
    const int t  = threadIdx.x % 160;
    if (t >= 150) return;
    const int b  = bn / NATOM;
    const int base = bn * NNB;
    float lo = 0.f, hi = 0.f;
#pragma unroll
    for (int j = 0; j < NNB; ++j) {
        if (maskn[base + j]) {
            const int a  = ag[base + j];
            const int bo = bg[base + j];
            u32 va = A2f[(size_t)(b * NATOM + a) * (HP / 2) + t];
            u32 vb = bnb[(size_t)(b * NBOND + bo) * (HP / 2) + t];
            lo += bflo(va) * bflo(vb);
            hi += bfhi(va) * bfhi(vb);
        }
    }
    float2 r;
    if (maska[bn]) {
        u32 s = selfF[(size_t)bn * (HP / 2) + t];
        r.x = bflo(s) * lo;
        r.y = bfhi(s) * hi;
    } else {
        r.x = 0.f; r.y = 0.f;
    }
    *reinterpret_cast<float2*>(out + (size_t)bn * HREAL + 2 * t) = r;
}

extern "C" void kernel_launch(void* const* d_in, const int* in_sizes, int n_in,
                              void* d_out, int out_size, void* d_ws, size_t ws_size,
                              hipStream_t stream) {
    const float* A1        = (const float*)d_in[0];
    const float* bond      = (const float*)d_in[1];
    const int*   ag        = (const int*)d_in[2];
    const int*   bg        = (const int*)d_in[3];
    const int*   maskn     = (const int*)d_in[6];
    const int*   maska     = (const int*)d_in[7];
    const float* W_fc1     = (const float*)d_in[8];
    const float* W_gc_nei  = (const float*)d_in[9];
    const float* b_gc_nei  = (const float*)d_in[10];
    const float* W_gc_atom = (const float*)d_in[11];
    const float* b_gc_atom = (const float*)d_in[12];
    const float* W_fc2a    = (const float*)d_in[13];
    const float* W_fc2b    = (const float*)d_in[14];
    const float* W_fc2     = (const float*)d_in[15];
    float* out = (float*)d_out;

    // ---- workspace carve-up ----
    char* p = (char*)d_ws;
    auto alloc = [&](size_t bytes) { char* r = p; p += (bytes + 63) & ~(size_t)63; return r; };
    __hip_bfloat16* A1b    = (__hip_bfloat16*)alloc((size_t)MA * 96 * 2);
    __hip_bfloat16* bondb  = (__hip_bfloat16*)alloc((size_t)MB * 32 * 2);
    __hip_bfloat16* af0    = (__hip_bfloat16*)alloc((size_t)MA * HP * 2);
    __hip_bfloat16* af1    = (__hip_bfloat16*)alloc((size_t)MA * HP * 2);
    __hip_bfloat16* Tb     = (__hip_bfloat16*)alloc((size_t)MA * HP * 2);
    __hip_bfloat16* neib   = (__hip_bfloat16*)alloc((size_t)MA * HP * 2);
    __hip_bfloat16* selfF  = (__hip_bfloat16*)alloc((size_t)MA * HP * 2);
    __hip_bfloat16* A2f    = (__hip_bfloat16*)alloc((size_t)MA * HP * 2);
    __hip_bfloat16* bondgc = (__hip_bfloat16*)alloc((size_t)MB * HP * 2);
    __hip_bfloat16* bnb    = (__hip_bfloat16*)alloc((size_t)MB * HP * 2);
    float*          U      = (float*)alloc((size_t)MA * HP * 4);        // fp32 af@W_gaTop + bias
    short8* pW1  = (short8*)alloc((size_t)NCT32 * 6  * 64 * 16);        // fc1          K=96
    short8* pWnu = (short8*)alloc((size_t)2 * NCT32 * 20 * 64 * 16);    // nei | gaTop  K=320, 20 ct
    short8* pWgb = (short8*)alloc((size_t)NCT32 * 20 * 64 * 16);        // gaBot        K=320
    short8* pWbd = (short8*)alloc((size_t)2 * NCT32 * 2 * 64 * 16);     // dual bond    K=32, 20 ct
    short8* pWfd = (short8*)alloc((size_t)2 * NCT32 * 20 * 64 * 16);    // fc2 | fc2a   K=320, 20 ct

    // ---- prep: convs + packs in one launch ----
    Prep cfg;
    cfg.a1src = A1;   cfg.a1dst = A1b;
    cfg.bsrc  = bond; cfg.bdst  = bondb;
    //                 W                                    dst                           Kreal KT  blk0
    cfg.j[0] = { W_fc1,                                  pW1,                          AF,    6,   0 };
    cfg.j[1] = { W_gc_nei,                               pWnu,                         HREAL, 20,  15 };
    cfg.j[2] = { W_gc_atom,                              pWnu + (size_t)NCT32*20*64,   HREAL, 20,  65 };
    cfg.j[3] = { W_gc_atom + (size_t)HREAL * HREAL,      pWgb,                         HREAL, 20, 115 };
    cfg.j[4] = { W_gc_nei + (size_t)HREAL * HREAL,       pWbd,                         BF,    2,  165 };
    cfg.j[5] = { W_fc2b,                                 pWbd + (size_t)NCT32*2*64,    BF,    2,  170 };
    cfg.j[6] = { W_fc2,                                  pWfd,                         HREAL, 20, 175 };
    cfg.j[7] = { W_fc2a,                                 pWfd + (size_t)NCT32*20*64,   HREAL, 20, 225 };
    prep_all<<<dim3(PREP_BLKS), dim3(256), 0, stream>>>(cfg);

    // ---- input GEMMs (fc1 + bond dual) in one launch ----
    k_input_gemms<<<dim3(FC1_BLKS + BOND_BLKS), dim3(128), 0, stream>>>(
        A1b, bondb, pW1, pWbd, b_gc_nei, af0, bondgc, bnb);

    const dim3 gNU(MA / 64, 10);   // (120,10) dual: Tb + U
    const dim3 gBOT(MA / 64, 5);   // (120,5)
    const dim3 t128(128);

    // ---- graph-conv iterations ----
    const __hip_bfloat16* af = af0;
    __hip_bfloat16* afn = af1;
    for (int it = 0; it < 2; ++it) {
        k_gemm_nu<<<gNU, t128, 0, stream>>>(af, pWnu, b_gc_atom, Tb, U);
        gather_relu_sum_bf<<<dim3(MA / 2), dim3(320), 0, stream>>>(
            (const u32*)Tb, (const u32*)bondgc, ag, bg, maskn, (u32*)neib);
        k_gemm_bot<<<gBOT, t128, 0, stream>>>(neib, pWgb, U, afn);
        const __hip_bfloat16* t = afn; afn = (__hip_bfloat16*)af; af = t;
    }

    // ---- final layer ----
    k_gemm_final<<<gNU, t128, 0, stream>>>(af, pWfd, selfF, A2f);
    final_bf<<<dim3(MA / 2), dim3(320), 0, stream>>>(
        (const u32*)A2f, (const u32*)bnb, (const u32*)selfF, ag, bg, maskn, maska, out);
}